// Round 10
// baseline (164.721 us; speedup 1.0000x reference)
//
#include <hip/hip_runtime.h>
#include <stdint.h>

typedef unsigned int u32;

using i32x8 = __attribute__((ext_vector_type(8))) int;
using f32x4 = __attribute__((ext_vector_type(4))) float;

#define NROWS 32768   // B*H*W*D / 256 rows after reshape(-1,256)
#define NDIM  256
#define KCODES 8192
#define ND_TOT 8388608
#define CBSCALE 8192.0f   // lifts codebook (+-1.2e-4) into e4m3 range; argmax invariant

// ---------------- prep: cb -> fp8, repacked MFMA-fragment-contiguous ----------------
// Output unit u (16 bytes) <-> (T, kh, s, lane), byte addr = u*16 with
//   T = u>>8 (16-code tile), kh = (u>>7)&1 (K-half), s = (u>>6)&1, lane = u&63.
// Source floats: code = T*16 + (lane&15);
//   off = code*256 + kh*128 + (lane>>4)*32 + s*16   (16 consecutive floats).
// Exactly the per-lane B-fragment byte order of mfma_scale_f32_16x16x128_f8f6f4,
// so the runtime kernel's loads are wave-contiguous 1KB dwordx4 bursts.
__global__ __launch_bounds__(256) void prep_cb8_kernel(const float* __restrict__ cb,
                                                       u32* __restrict__ cbb8,
                                                       float* __restrict__ loss) {
    if (blockIdx.x == 0 && threadIdx.x == 0) loss[0] = 0.f;   // out re-poisoned each call
    int u = blockIdx.x * 256 + threadIdx.x;                   // 0..131071
    int T = u >> 8, rest = u & 255;
    int kh = rest >> 7, s = (rest >> 6) & 1, lane = rest & 63;
    int code = T * 16 + (lane & 15);
    const float* src = cb + (size_t)code * NDIM + kh * 128 + (lane >> 4) * 32 + s * 16;
    uint4 o;
    #pragma unroll
    for (int q = 0; q < 4; q++) {
        float4 v = *(const float4*)(src + q * 4);
        int r = __builtin_amdgcn_cvt_pk_fp8_f32(v.x * CBSCALE, v.y * CBSCALE, 0, false);
        r     = __builtin_amdgcn_cvt_pk_fp8_f32(v.z * CBSCALE, v.w * CBSCALE, r, true);
        ((u32*)&o)[q] = (u32)r;
    }
    *(uint4*)((char*)cbb8 + (size_t)u * 16) = o;
}

// ---------------- fully fused: GEMM + argmax + gather + ST + loss ----------------
// R10 = 128-ROW WAVES (2x arithmetic intensity per load). Evidence: R8
// (L2 anti-hotspot, +4%) and R9 (L1 pair-sharing, halved L2 bytes/CU, 0%)
// prove the cost is NOT byte sourcing -- it scales with the per-CU VMEM
// work itself (32 wave-loads/CU/phase). Fix the ratio: each wave now owns
// 128 m-rows x a code QUARTER, so one 4KB tile feeds 16 MFMA instead of 8.
// Per-CU loads/phase 32->16, codebook traffic 4MB->2MB, matrix work per
// phase doubles. Block = 256 thr / 4 waves (wave w = quarter q=w), grid
// 256 = 1 block/CU -> 1 wave/SIMD; ~310 VGPR (A8=128, 4 bufs=64, 2 acc
// sets=64, mkey=32) under launch_bounds(256,1)'s 512 budget -- occupancy
// is intentionally 4 waves/CU; all latency hiding is the forced pipeline.
// With no co-wave, lag-1 argmax is now ESSENTIAL (otherwise the acc->amax
// dependency tail bubbles the matrix pipe between phases).
// Floor: 128 phases x 552 matrix-cyc = 29.5us; predicted 48-62us.
// Mechanisms carried: asm-forced 4-buffer/3-deep pipeline ("=&v" early-
// clobber; plain "=v" faulted), vmcnt(12)+sched_barrier(0) waits (rule
// #18), peeled descending-wait tail (zero dead loads), per-(block,q) ring
// rotation, bias-C acc-init (+2048 -> float order == int order).
__global__ __launch_bounds__(256, 1) void vq_fused_kernel(const float* __restrict__ z,
                                                          const float* __restrict__ cb,
                                                          const u32* __restrict__ cbb8,
                                                          float* __restrict__ out) {
    __shared__ u32 keys_lds[4][128];                 // [quarter][block row]
    __shared__ float red[4];

    int m0  = blockIdx.x * 128;
    int tid = threadIdx.x;
    int lane = tid & 63, w = tid >> 6;               // w = 0..3 = code-quarter
    int qbase = w * (KCODES / 4);
    int l15 = lane & 15, quad = lane >> 4;
    int rot = (((int)blockIdx.x >> 3) + (((int)blockIdx.x & 7) << 4) + (w << 5)) & 127;

    // ---- A prologue: ALL 128 block rows x 256 K fp32 -> fp8 in 128 VGPRs ----
    i32x8 A8[2][8];              // [kh(128-wide)][i-frag(16 rows)]
    #pragma unroll
    for (int kh = 0; kh < 2; kh++)
        #pragma unroll
        for (int i = 0; i < 8; i++) {
            const float* p = z + (size_t)(m0 + i * 16 + l15) * NDIM + kh * 128 + quad * 32;
            union { u32 u[8]; i32x8 v; } c;
            #pragma unroll
            for (int g = 0; g < 4; g++) {
                float4 x = *(const float4*)(p + g * 8);
                float4 y = *(const float4*)(p + g * 8 + 4);
                int r = __builtin_amdgcn_cvt_pk_fp8_f32(x.x, x.y, 0, false);
                r     = __builtin_amdgcn_cvt_pk_fp8_f32(x.z, x.w, r, true);
                c.u[g * 2] = (u32)r;
                r = __builtin_amdgcn_cvt_pk_fp8_f32(y.x, y.y, 0, false);
                r = __builtin_amdgcn_cvt_pk_fp8_f32(y.z, y.w, r, true);
                c.u[g * 2 + 1] = (u32)r;
            }
            A8[kh][i] = c.v;
        }
    // drain prologue loads so the raw vmcnt(N) below counts ONLY B-tile loads
    __asm__ volatile("s_waitcnt vmcnt(0)" ::: "memory");
    __builtin_amdgcn_sched_barrier(0);

    // ---- B stream: packed fragment layout, per-lane base + tile offsets ----
    // tile t of quarter w lives at bytes (w*128 + t)*4096; lane slice = +lane*16.
    // pieces (kh,s) at byte offsets +0 / +1024 / +2048 / +3072.
    const char* lp = (const char*)cbb8 + (size_t)(w * 128) * 4096 + (size_t)lane * 16;

    auto loadt = [&](int4* b, int n) {
        int t = (n + rot) & 127;             // rotated ring position
        const char* pa = lp + (size_t)t * 4096;
        asm volatile("global_load_dwordx4 %0, %4, off\n\t"
                     "global_load_dwordx4 %1, %4, off offset:1024\n\t"
                     "global_load_dwordx4 %2, %4, off offset:2048\n\t"
                     "global_load_dwordx4 %3, %4, off offset:3072"
                     : "=&v"(b[0]), "=&v"(b[1]), "=&v"(b[2]), "=&v"(b[3])
                     : "v"(pa));
    };
    // buffer-resident waits; sched_barrier stops consumers hoisting (rule #18)
    auto wait12 = [&]() { asm volatile("s_waitcnt vmcnt(12)" ::: "memory");
                          __builtin_amdgcn_sched_barrier(0); };
    auto wait8  = [&]() { asm volatile("s_waitcnt vmcnt(8)"  ::: "memory");
                          __builtin_amdgcn_sched_barrier(0); };
    auto wait4  = [&]() { asm volatile("s_waitcnt vmcnt(4)"  ::: "memory");
                          __builtin_amdgcn_sched_barrier(0); };
    auto wait0  = [&]() { asm volatile("s_waitcnt vmcnt(0)"  ::: "memory");
                          __builtin_amdgcn_sched_barrier(0); };

    const f32x4 bias4 = {2048.f, 2048.f, 2048.f, 2048.f};
    float mkey[32];
    #pragma unroll
    for (int s = 0; s < 32; s++) mkey[s] = 0.f;

    // MFMA for one 16-code tile into the given acc set (8 i-frags = 128 rows)
    auto domfma = [&](f32x4* acc, const int4* b) {
        union { int4 q2[2]; i32x8 v; } u0, u1;
        u0.q2[0] = b[0]; u0.q2[1] = b[1];    // kh=0 fragment (32B/lane)
        u1.q2[0] = b[2]; u1.q2[1] = b[3];    // kh=1 fragment
        #pragma unroll
        for (int i = 0; i < 8; i++)
            acc[i] = __builtin_amdgcn_mfma_scale_f32_16x16x128_f8f6f4(
                         A8[0][i], u0.v, bias4, 0, 0, 0, 0x7F7F7F7F, 0, 0x7F7F7F7F);
        #pragma unroll
        for (int i = 0; i < 8; i++)
            acc[i] = __builtin_amdgcn_mfma_scale_f32_16x16x128_f8f6f4(
                         A8[1][i], u1.v, acc[i], 0, 0, 0, 0x7F7F7F7F, 0, 0x7F7F7F7F);
    };
    // packed-key argmax for a PREVIOUS tile (data ready a full phase ago)
    auto amax = [&](const f32x4* acc, int n) {
        int t = (n + rot) & 127;             // absolute tile id (rotated)
        int cb0 = qbase + t * 16 + l15;
        #pragma unroll
        for (int i = 0; i < 8; i++)
            #pragma unroll
            for (int r = 0; r < 4; r++) {
                u32 p = (__float_as_uint(acc[i][r]) & 0xFFFFE000u) | (u32)cb0;
                mkey[i * 4 + r] = fmaxf(mkey[i * 4 + r], __uint_as_float(p));
            }
    };

    // ---- main loop: 128 tiles, 4 forced reg buffers, 3-deep prefetch,
    //      lag-1 argmax on two acc sets (even tile -> accA, odd -> accB) ----
    f32x4 accA[8], accB[8];
    int4 bb0[4], bb1[4], bb2[4], bb3[4];
    loadt(bb0, 0); loadt(bb1, 1); loadt(bb2, 2);   // prime: 12 loads in flight

    // peeled first group: tiles 0..3 (tile 0 has no lag-1 argmax)
    loadt(bb3, 3);  wait12();  domfma(accA, bb0);
    loadt(bb0, 4);  wait12();  domfma(accB, bb1);  amax(accA, 0);
    loadt(bb1, 5);  wait12();  domfma(accA, bb2);  amax(accB, 1);
    loadt(bb2, 6);  wait12();  domfma(accB, bb3);  amax(accA, 2);

    #pragma unroll 1
    for (int n = 4; n < 124; n += 4) {
        loadt(bb3, n + 3);  wait12();  domfma(accA, bb0);  amax(accB, n - 1);
        loadt(bb0, n + 4);  wait12();  domfma(accB, bb1);  amax(accA, n);
        loadt(bb1, n + 5);  wait12();  domfma(accA, bb2);  amax(accB, n + 1);
        loadt(bb2, n + 6);  wait12();  domfma(accB, bb3);  amax(accA, n + 2);
    }
    // ---- peeled tail: tiles 124..127, descending waits, zero dead loads ----
    loadt(bb3, 127);
    wait12();  domfma(accA, bb0);  amax(accB, 123);
    wait8();   domfma(accB, bb1);  amax(accA, 124);
    wait4();   domfma(accA, bb2);  amax(accB, 125);
    wait0();   domfma(accB, bb3);  amax(accA, 126);
    amax(accB, 127);

    // ---- merge: reduce over 16 col-lanes, stash per-row keys in LDS ----
    // acc[i][r] is row i*16 + quad*4 + r, col-lane l15; 32 s-slots, each
    // 16-lane group elects one writer per (s&15); lane l15 writes s and s+16.
    #pragma unroll
    for (int s = 0; s < 32; s++) {
        float v = mkey[s];
        #pragma unroll
        for (int sh = 1; sh < 16; sh <<= 1)
            v = fmaxf(v, __shfl_xor(v, sh, 64));
        if (l15 == (s & 15))
            keys_lds[w][(s >> 2) * 16 + quad * 4 + (s & 3)] = __float_as_uint(v);
    }
    __syncthreads();

    // ---- fused gather + straight-through + loss (block's own 128 rows) ----
    int d = lane * 4;
    float sacc = 0.f;
    #pragma unroll
    for (int g = 0; g < 32; g++) {
        int rl = w * 32 + g;                 // 4 waves x 32 rows = 128
        u32 k0 = keys_lds[0][rl], k1 = keys_lds[1][rl];
        u32 k2 = keys_lds[2][rl], k3 = keys_lds[3][rl];
        u32 a = k0 > k1 ? k0 : k1;
        u32 b = k2 > k3 ? k2 : k3;
        u32 idx = (a > b ? a : b) & 0x1FFFu;
        size_t zoff = (size_t)(m0 + rl) * NDIM + d;
        float4 zv = *(const float4*)(z + zoff);
        float4 qv = *(const float4*)(cb + (size_t)idx * NDIM + d);
        float4 o;
        o.x = zv.x + (qv.x - zv.x);           // straight-through, matches ref fp ops
        o.y = zv.y + (qv.y - zv.y);
        o.z = zv.z + (qv.z - zv.z);
        o.w = zv.w + (qv.w - zv.w);
        *(float4*)(out + zoff) = o;
        float dx = zv.x - qv.x, dy = zv.y - qv.y, dz = zv.z - qv.z, dw = zv.w - qv.w;
        sacc += dx * dx + dy * dy + dz * dz + dw * dw;
    }
    #pragma unroll
    for (int off = 32; off > 0; off >>= 1) sacc += __shfl_down(sacc, off, 64);
    if (lane == 0) red[w] = sacc;
    __syncthreads();
    if (tid == 0) {
        float tot = (red[0] + red[1]) + (red[2] + red[3]);
        atomicAdd(out + ND_TOT, tot * (1.25f / 8388608.f));   // (0.25+1.0)*mean
    }
}

extern "C" void kernel_launch(void* const* d_in, const int* in_sizes, int n_in,
                              void* d_out, int out_size, void* d_ws, size_t ws_size,
                              hipStream_t stream) {
    const float* z  = (const float*)d_in[0];   // 8*256*64*64 fp32
    const float* cb = (const float*)d_in[1];   // 8192*256 fp32
    float* out = (float*)d_out;                // 8388608 quantized_st + 1 loss

    u32* cbb8 = (u32*)d_ws;                    // 2 MB (cb fp8, fragment-packed)

    prep_cb8_kernel<<<KCODES * NDIM / 16 / 256, 256, 0, stream>>>(cb, cbb8, out + ND_TOT);
    vq_fused_kernel<<<NROWS / 128, 256, 0, stream>>>(z, cb, cbb8, out);
}

// Round 13
// 154.725 us; speedup vs baseline: 1.0646x; 1.0646x over previous
//
#include <hip/hip_runtime.h>
#include <stdint.h>

typedef unsigned int u32;

using i32x8 = __attribute__((ext_vector_type(8))) int;
using f32x4 = __attribute__((ext_vector_type(4))) float;

#define NROWS 32768   // B*H*W*D / 256 rows after reshape(-1,256)
#define NDIM  256
#define KCODES 8192
#define ND_TOT 8388608
#define CBSCALE 8192.0f   // lifts codebook (+-1.2e-4) into e4m3 range; argmax invariant

// ---------------- prep: cb -> fp8, repacked MFMA-fragment-contiguous ----------------
// Output unit u (16 bytes) <-> (T, kh, s, lane), byte addr = u*16 with
//   T = u>>8 (16-code tile), kh = (u>>7)&1 (K-half), s = (u>>6)&1, lane = u&63.
// Source floats: code = T*16 + (lane&15);
//   off = code*256 + kh*128 + (lane>>4)*32 + s*16   (16 consecutive floats).
// Exactly the per-lane B-fragment byte order of mfma_scale_f32_16x16x128_f8f6f4,
// so the runtime kernel's loads are wave-contiguous 1KB dwordx4 bursts.
__global__ __launch_bounds__(256) void prep_cb8_kernel(const float* __restrict__ cb,
                                                       u32* __restrict__ cbb8,
                                                       float* __restrict__ loss) {
    if (blockIdx.x == 0 && threadIdx.x == 0) loss[0] = 0.f;   // out re-poisoned each call
    int u = blockIdx.x * 256 + threadIdx.x;                   // 0..131071
    int T = u >> 8, rest = u & 255;
    int kh = rest >> 7, s = (rest >> 6) & 1, lane = rest & 63;
    int code = T * 16 + (lane & 15);
    const float* src = cb + (size_t)code * NDIM + kh * 128 + (lane >> 4) * 32 + s * 16;
    uint4 o;
    #pragma unroll
    for (int q = 0; q < 4; q++) {
        float4 v = *(const float4*)(src + q * 4);
        int r = __builtin_amdgcn_cvt_pk_fp8_f32(v.x * CBSCALE, v.y * CBSCALE, 0, false);
        r     = __builtin_amdgcn_cvt_pk_fp8_f32(v.z * CBSCALE, v.w * CBSCALE, r, true);
        ((u32*)&o)[q] = (u32)r;
    }
    *(uint4*)((char*)cbb8 + (size_t)u * 16) = o;
}

// ---------------- fully fused: GEMM + argmax + gather + ST + loss ----------------
// R13 = R12's super-phase schedule with STATIC buffer selection. R12
// aborted at runtime: `bufs[p%3]` (runtime-selected pointers to register
// arrays) made pb0/pb1/pb2 addressable -> demoted to scratch (rule #20).
// The asm "=&v" outputs then went through temp VGPRs copied to scratch
// right after the (async!) asm block; the temps were reallocated -- into
// later loads' address pairs -- before the load data landed -> data
// clobbered a live address -> wild access -> abort (same class as R5).
// Fix: unroll the main loop by 3 super-phases so the pb1->pb2->pb0
// rotation is spelled with NAMED arrays only; peel p=61; tail 62/63.
// Schedule, vmcnt arithmetic (pair q -> buffer q%3), and all other
// structure identical to R12's intent.
//
// R11 rationale (unchanged): R8 base (78.6us; 2 blocks/CU x 4 waves x 64
// rows, quarter codebook per wave) + SUPER-PHASES + SETPRIO. Evidence: R9
// (byte sourcing) null, R10 (half the loads at 1 wave/SIMD) -20% -> the
// residual ~490cyc/phase stall is per-phase FIXED overhead x 128 phases
// (s_waitcnt drain 156-332cyc even L2-warm (m135) + 2 sched_barrier walls
// + both co-waves' MFMA/VALU issue bursts colliding).
//   - 64 super-phases over 8KB PAIRS: 8 loads/pair (two 4-load asm blocks,
//     offset: max 3072 -- 13-bit signed limit, R11 lesson), 3 pair-buffers
//     (96 VGPR), depth-2 prefetch, steady vmcnt(16). Waits/fences halve.
//   - per super-phase: sp1[8 MFMA]sp0, amax(prev), sp1[8 MFMA]sp0,
//     amax(cur) -- every amax one full 276-cyc MFMA cluster from its
//     producer (lag-1 preserved); setprio(1) around MFMA clusters gives
//     the CU scheduler a role split between the 2 co-resident waves (T5).
//   - VGPR ~230 < 256 -> 2 waves/SIMD PRESERVED (R10's occupancy lesson).
// Carried: "=&v" early-clobber asm loads (plain "=v" faulted), sched_
// barrier(0) after waits (rule #18), peeled tail w/ descending waits and
// zero dead loads, per-(block,wave) pair-ring rotation, bias-C acc-init
// (+2048 -> scores positive -> float order == int order).
__global__ __launch_bounds__(256, 2) void vq_fused_kernel(const float* __restrict__ z,
                                                          const float* __restrict__ cb,
                                                          const u32* __restrict__ cbb8,
                                                          float* __restrict__ out) {
    __shared__ u32 keys_lds[4][64];                  // [wave/quarter][row]
    __shared__ float red[4];

    int m0  = blockIdx.x * 64;
    int tid = threadIdx.x;
    int lane = tid & 63, w = tid >> 6;               // w = code-quarter
    int qbase = w * (KCODES / 4);
    int l15 = lane & 15, quad = lane >> 4;
    int rotp = (((int)blockIdx.x >> 3) + (((int)blockIdx.x & 7) << 3) + (w << 4)) & 63;

    // ---- A prologue: ALL 64 block rows x 256 K fp32 -> fp8 in 64 VGPRs ----
    i32x8 A8[2][4];              // [kh(128-wide)][i-frag(16 rows)]
    #pragma unroll
    for (int kh = 0; kh < 2; kh++)
        #pragma unroll
        for (int i = 0; i < 4; i++) {
            const float* p = z + (size_t)(m0 + i * 16 + l15) * NDIM + kh * 128 + quad * 32;
            union { u32 u[8]; i32x8 v; } c;
            #pragma unroll
            for (int g = 0; g < 4; g++) {
                float4 x = *(const float4*)(p + g * 8);
                float4 y = *(const float4*)(p + g * 8 + 4);
                int r = __builtin_amdgcn_cvt_pk_fp8_f32(x.x, x.y, 0, false);
                r     = __builtin_amdgcn_cvt_pk_fp8_f32(x.z, x.w, r, true);
                c.u[g * 2] = (u32)r;
                r = __builtin_amdgcn_cvt_pk_fp8_f32(y.x, y.y, 0, false);
                r = __builtin_amdgcn_cvt_pk_fp8_f32(y.z, y.w, r, true);
                c.u[g * 2 + 1] = (u32)r;
            }
            A8[kh][i] = c.v;
        }
    // drain prologue loads so the raw vmcnt(N) below counts ONLY B-pair loads
    __asm__ volatile("s_waitcnt vmcnt(0)" ::: "memory");
    __builtin_amdgcn_sched_barrier(0);

    // ---- B stream: packed fragment layout; PAIR p = tiles 2p,2p+1 = 8KB ----
    // pair t of quarter w at bytes (w*64 + t)*8192; lane slice = +lane*16;
    // 8 pieces at +0/+1024/.../+7168 (two asm blocks, offsets 0..3072 each).
    const char* lp = (const char*)cbb8 + (size_t)(w * 64) * 8192 + (size_t)lane * 16;

    auto load4 = [&](int4* b, const char* pa) {
        asm volatile("global_load_dwordx4 %0, %4, off\n\t"
                     "global_load_dwordx4 %1, %4, off offset:1024\n\t"
                     "global_load_dwordx4 %2, %4, off offset:2048\n\t"
                     "global_load_dwordx4 %3, %4, off offset:3072"
                     : "=&v"(b[0]), "=&v"(b[1]), "=&v"(b[2]), "=&v"(b[3])
                     : "v"(pa));
    };
    auto loadpair = [&](int4* b, int p) {
        int t = (p + rotp) & 63;             // rotated pair-ring position
        const char* pa = lp + (size_t)t * 8192;
        load4(b, pa);
        load4(b + 4, pa + 4096);
    };
    // pair-resident waits; sched_barrier stops consumers hoisting (rule #18)
    auto wait16 = [&]() { asm volatile("s_waitcnt vmcnt(16)" ::: "memory");
                          __builtin_amdgcn_sched_barrier(0); };
    auto wait8  = [&]() { asm volatile("s_waitcnt vmcnt(8)"  ::: "memory");
                          __builtin_amdgcn_sched_barrier(0); };
    auto wait0  = [&]() { asm volatile("s_waitcnt vmcnt(0)"  ::: "memory");
                          __builtin_amdgcn_sched_barrier(0); };

    const f32x4 bias4 = {2048.f, 2048.f, 2048.f, 2048.f};
    float mkey[16];
    #pragma unroll
    for (int s = 0; s < 16; s++) mkey[s] = 0.f;

    // MFMA cluster for one 16-code tile (b = 4 int4 fragments), setprio-wrapped
    auto domfma = [&](f32x4* acc, const int4* b) {
        union { int4 q2[2]; i32x8 v; } u0, u1;
        u0.q2[0] = b[0]; u0.q2[1] = b[1];    // kh=0 fragment (32B/lane)
        u1.q2[0] = b[2]; u1.q2[1] = b[3];    // kh=1 fragment
        __builtin_amdgcn_s_setprio(1);
        #pragma unroll
        for (int i = 0; i < 4; i++)
            acc[i] = __builtin_amdgcn_mfma_scale_f32_16x16x128_f8f6f4(
                         A8[0][i], u0.v, bias4, 0, 0, 0, 0x7F7F7F7F, 0, 0x7F7F7F7F);
        #pragma unroll
        for (int i = 0; i < 4; i++)
            acc[i] = __builtin_amdgcn_mfma_scale_f32_16x16x128_f8f6f4(
                         A8[1][i], u1.v, acc[i], 0, 0, 0, 0x7F7F7F7F, 0, 0x7F7F7F7F);
        __builtin_amdgcn_s_setprio(0);
    };
    // packed-key argmax for tile index (p, half) -- producer cluster is one
    // full MFMA cluster in the past
    auto amax = [&](const f32x4* acc, int p, int half) {
        int t = 2 * ((p + rotp) & 63) + half;      // absolute 16-code tile id
        int cb0 = qbase + t * 16 + l15;
        #pragma unroll
        for (int i = 0; i < 4; i++)
            #pragma unroll
            for (int r = 0; r < 4; r++) {
                u32 pk = (__float_as_uint(acc[i][r]) & 0xFFFFE000u) | (u32)cb0;
                mkey[i * 4 + r] = fmaxf(mkey[i * 4 + r], __uint_as_float(pk));
            }
    };

    // ---- main loop: 64 pairs, 3 NAMED pair-buffers (pair q -> buffer q%3),
    //      depth-2 prefetch, unroll-by-3 so selection is compile-time ----
    f32x4 accA[4], accB[4];
    int4 pb0[8], pb1[8], pb2[8];
    loadpair(pb0, 0); loadpair(pb1, 1);            // prime: 16 loads in flight

    // p=0 (no amax for previous yet); cur = pb0
    loadpair(pb2, 2);
    wait16();
    domfma(accA, pb0);                              // tile (0,lo)
    domfma(accB, pb0 + 4);                          // tile (0,hi)
    amax(accA, 0, 0);

    #pragma unroll 1
    for (int p = 1; p <= 58; p += 3) {
        // p % 3 == 1: cur = pb1, prefetch -> pb0
        loadpair(pb0, p + 2);   wait16();
        domfma(accA, pb1);      amax(accB, p - 1, 1);
        domfma(accB, pb1 + 4);  amax(accA, p, 0);
        // p+1 % 3 == 2: cur = pb2, prefetch -> pb1
        loadpair(pb1, p + 3);   wait16();
        domfma(accA, pb2);      amax(accB, p, 1);
        domfma(accB, pb2 + 4);  amax(accA, p + 1, 0);
        // p+2 % 3 == 0: cur = pb0, prefetch -> pb2
        loadpair(pb2, p + 4);   wait16();
        domfma(accA, pb0);      amax(accB, p + 1, 1);
        domfma(accB, pb0 + 4);  amax(accA, p + 2, 0);
    }
    // peeled p=61 (61 % 3 == 1): cur = pb1, prefetch final pair 63 -> pb0
    loadpair(pb0, 63);  wait16();
    domfma(accA, pb1);      amax(accB, 60, 1);
    domfma(accB, pb1 + 4);  amax(accA, 61, 0);
    // ---- peeled tail: pairs 62 (pb2), 63 (pb0) -- descending waits ----
    wait8();
    domfma(accA, pb2);      amax(accB, 61, 1);
    domfma(accB, pb2 + 4);  amax(accA, 62, 0);
    wait0();
    domfma(accA, pb0);      amax(accB, 62, 1);
    domfma(accB, pb0 + 4);  amax(accA, 63, 0);
    amax(accB, 63, 1);

    // ---- merge: reduce over 16 col-lanes, stash per-row keys in LDS ----
    #pragma unroll
    for (int s = 0; s < 16; s++) {
        float v = mkey[s];
        #pragma unroll
        for (int sh = 1; sh < 16; sh <<= 1)
            v = fmaxf(v, __shfl_xor(v, sh, 64));
        if (l15 == s)    // one writer per 16-lane group (4 quads -> 4 rows)
            keys_lds[w][(s >> 2) * 16 + quad * 4 + (s & 3)] = __float_as_uint(v);
    }
    __syncthreads();

    // ---- fused gather + straight-through + loss (block's own 64 rows) ----
    int d = lane * 4;
    float sacc = 0.f;
    #pragma unroll
    for (int g = 0; g < 16; g++) {
        int rl = w * 16 + g;
        u32 k0 = keys_lds[0][rl], k1 = keys_lds[1][rl];
        u32 k2 = keys_lds[2][rl], k3 = keys_lds[3][rl];
        u32 a = k0 > k1 ? k0 : k1;
        u32 b = k2 > k3 ? k2 : k3;
        u32 idx = (a > b ? a : b) & 0x1FFFu;
        size_t zoff = (size_t)(m0 + rl) * NDIM + d;
        float4 zv = *(const float4*)(z + zoff);
        float4 qv = *(const float4*)(cb + (size_t)idx * NDIM + d);
        float4 o;
        o.x = zv.x + (qv.x - zv.x);           // straight-through, matches ref fp ops
        o.y = zv.y + (qv.y - zv.y);
        o.z = zv.z + (qv.z - zv.z);
        o.w = zv.w + (qv.w - zv.w);
        *(float4*)(out + zoff) = o;
        float dx = zv.x - qv.x, dy = zv.y - qv.y, dz = zv.z - qv.z, dw = zv.w - qv.w;
        sacc += dx * dx + dy * dy + dz * dz + dw * dw;
    }
    #pragma unroll
    for (int off = 32; off > 0; off >>= 1) sacc += __shfl_down(sacc, off, 64);
    if (lane == 0) red[w] = sacc;
    __syncthreads();
    if (tid == 0) {
        float tot = (red[0] + red[1]) + (red[2] + red[3]);
        atomicAdd(out + ND_TOT, tot * (1.25f / 8388608.f));   // (0.25+1.0)*mean
    }
}

extern "C" void kernel_launch(void* const* d_in, const int* in_sizes, int n_in,
                              void* d_out, int out_size, void* d_ws, size_t ws_size,
                              hipStream_t stream) {
    const float* z  = (const float*)d_in[0];   // 8*256*64*64 fp32
    const float* cb = (const float*)d_in[1];   // 8192*256 fp32
    float* out = (float*)d_out;                // 8388608 quantized_st + 1 loss

    u32* cbb8 = (u32*)d_ws;                    // 2 MB (cb fp8, fragment-packed)

    prep_cb8_kernel<<<KCODES * NDIM / 16 / 256, 256, 0, stream>>>(cb, cbb8, out + ND_TOT);
    vq_fused_kernel<<<NROWS / 64, 256, 0, stream>>>(z, cb, cbb8, out);
}